// Round 1
// baseline (5003.458 us; speedup 1.0000x reference)
//
#include <hip/hip_runtime.h>
#include <hip/hip_bf16.h>
#include <cstdint>
#include <cstddef>

// Problem constants
#define NB 512
#define NR 1152
#define NC 8
#define NJ 10
#define NO 16
#define NJO 160   // NJ*NO

typedef unsigned int uint32;
typedef unsigned short ushort16;

// ---- bf16 helpers (RNE pack, bit-shift unpack) ----
__device__ __forceinline__ uint32 f2bf(float f) {
    uint32 x = __float_as_uint(f);
    return (x + 0x7fffu + ((x >> 16) & 1u)) >> 16;
}
__device__ __forceinline__ float bflo(uint32 w) { return __uint_as_float(w << 16); }
__device__ __forceinline__ float bfhi(uint32 w) { return __uint_as_float(w & 0xffff0000u); }

// k must be a compile-time-foldable expression (fully unrolled loops only)
#define UVAL(k) (((k) & 1) ? bfhi(u32[(k) >> 1]) : bflo(u32[(k) >> 1]))

// ============================================================================
// Kernel 1: u_hat[b,r,j,o] = sum_c W[r,j,o,c] * x[b,r,c], stored bf16.
// One block per r. W[r] (5KB) -> LDS transposed [c][jo]; x[:,r,:] (16KB) -> LDS.
// Thread owns a (j,o)-pair column; W coefficients live in registers; inner
// loop over b reads x via LDS broadcast (ds_read_b128) and stores ushort2.
// ============================================================================
__global__ __launch_bounds__(320) void uhat_kernel(const float* __restrict__ x,
                                                   const float* __restrict__ W,
                                                   uint32* __restrict__ u /* packed bf16 pairs */) {
    const int r = blockIdx.x;
    const int t = threadIdx.x;

    __shared__ float Ws[NC][NJO];   // 5 KB, transposed: [c][jo]
    __shared__ float xs[NB][NC];    // 16 KB

    // stage W[r]: 1280 contiguous floats
    for (int i = t; i < NJO * NC; i += 320) {
        Ws[i & 7][i >> 3] = W[(size_t)r * (NJO * NC) + i];
    }
    // stage x[:, r, :]: 512 rows of 8 contiguous floats (strided by 9216)
    for (int i = t; i < NB * NC; i += 320) {
        int b = i >> 3, c = i & 7;
        xs[b][c] = x[(size_t)b * (NR * NC) + r * NC + c];
    }
    __syncthreads();

    const int jo2  = t % 80;   // pair index: handles jo = 2*jo2, 2*jo2+1
    const int half = t / 80;   // 0..3

    float w0[8], w1[8];
#pragma unroll
    for (int c = 0; c < 8; ++c) {
        w0[c] = Ws[c][2 * jo2];
        w1[c] = Ws[c][2 * jo2 + 1];
    }

    for (int b = half; b < NB; b += 4) {
        const float4* xp = (const float4*)xs[b];
        float4 xa = xp[0], xb = xp[1];
        float a0 = w0[0] * xa.x + w0[1] * xa.y + w0[2] * xa.z + w0[3] * xa.w
                 + w0[4] * xb.x + w0[5] * xb.y + w0[6] * xb.z + w0[7] * xb.w;
        float a1 = w1[0] * xa.x + w1[1] * xa.y + w1[2] * xa.z + w1[3] * xa.w
                 + w1[4] * xb.x + w1[5] * xb.y + w1[6] * xb.z + w1[7] * xb.w;
        uint32 p = f2bf(a0) | (f2bf(a1) << 16);
        u[(size_t)(b * NR + r) * 80 + jo2] = p;
    }
}

// ============================================================================
// Routing pass kernel. One thread per (b, r). Grid = (R/384, B), block = 384.
//   b_ij(r,j)   = sum_o u[r,j,o] * vsum[b,j,o]   (vsum = v0, or v0+v1)
//   c(r,j)      = softmax_j(b_ij)                (UNIFORM pass: c = 1/J)
//   s[b,j,o]   += sum_r c(r,j) * u[r,j,o]        (LDS ds_add_f32 tile, then
//                                                 one global atomic per jo)
// ============================================================================
template <bool UNIFORM>
__global__ __launch_bounds__(384) void pass_kernel(const uint32* __restrict__ u,
                                                   const float* __restrict__ vsum,
                                                   float* __restrict__ s) {
    const int b = blockIdx.y;
    const int t = threadIdx.x;
    const int r = blockIdx.x * 384 + t;

    __shared__ float vs[NJO];
    __shared__ float sl[NJO];
    if (t < NJO) {
        sl[t] = 0.0f;
        if (!UNIFORM) vs[t] = vsum[b * NJO + t];
    }
    __syncthreads();

    // load this (b,r)'s 160 bf16 u values: 20 x dwordx4, fully coalesced
    uint32 u32[80];
    const uint4* up = (const uint4*)(u + (size_t)(b * NR + r) * 80);
#pragma unroll
    for (int i = 0; i < 20; ++i) {
        uint4 q = up[i];
        u32[4 * i + 0] = q.x;
        u32[4 * i + 1] = q.y;
        u32[4 * i + 2] = q.z;
        u32[4 * i + 3] = q.w;
    }

    float cj[NJ];
    if (UNIFORM) {
#pragma unroll
        for (int j = 0; j < NJ; ++j) cj[j] = 1.0f / NJ;
    } else {
        float bj[NJ];
        const float4* vp = (const float4*)vs;
#pragma unroll
        for (int j = 0; j < NJ; ++j) {
            float acc = 0.0f;
#pragma unroll
            for (int q = 0; q < 4; ++q) {
                float4 v4 = vp[j * 4 + q];
                acc += v4.x * UVAL(j * 16 + q * 4 + 0);
                acc += v4.y * UVAL(j * 16 + q * 4 + 1);
                acc += v4.z * UVAL(j * 16 + q * 4 + 2);
                acc += v4.w * UVAL(j * 16 + q * 4 + 3);
            }
            bj[j] = acc;
        }
        float m = bj[0];
#pragma unroll
        for (int j = 1; j < NJ; ++j) m = fmaxf(m, bj[j]);
        float sum = 0.0f;
#pragma unroll
        for (int j = 0; j < NJ; ++j) {
            float e = __expf(bj[j] - m);
            cj[j] = e;
            sum += e;
        }
        float inv = 1.0f / sum;
#pragma unroll
        for (int j = 0; j < NJ; ++j) cj[j] *= inv;
    }

    // weighted accumulate into LDS s-tile
#pragma unroll
    for (int j = 0; j < NJ; ++j) {
#pragma unroll
        for (int o = 0; o < NO; ++o) {
            atomicAdd(&sl[j * 16 + o], cj[j] * UVAL(j * 16 + o));
        }
    }
    __syncthreads();
    if (t < NJO) atomicAdd(&s[b * NJO + t], sl[t]);
}

// ============================================================================
// Squash: per (b,j): sq = sum_o s^2; v = (sq/(1+sq)) * s * rsqrt(sq + 1e-8).
// FINAL=false: vacc += v (running vsum). FINAL=true: write v to out.
// ============================================================================
template <bool FINAL>
__global__ __launch_bounds__(256) void squash_kernel(const float* __restrict__ s,
                                                     float* __restrict__ vacc) {
    const int idx = blockIdx.x * 256 + threadIdx.x;  // < 81920
    float val = s[idx];
    float sq = val * val;
#pragma unroll
    for (int off = 1; off < 16; off <<= 1) sq += __shfl_xor(sq, off, 16);
    float scale = (sq / (1.0f + sq)) * rsqrtf(sq + 1e-8f);
    float v = val * scale;
    if (FINAL) vacc[idx] = v;
    else       vacc[idx] += v;
}

// ============================================================================
extern "C" void kernel_launch(void* const* d_in, const int* in_sizes, int n_in,
                              void* d_out, int out_size, void* d_ws, size_t ws_size,
                              hipStream_t stream) {
    (void)in_sizes; (void)n_in; (void)out_size; (void)ws_size;

    const float* x = (const float*)d_in[0];  // [B,R,C]
    const float* W = (const float*)d_in[1];  // [R,J,O,C]
    float* out = (float*)d_out;              // [B,J,O,1] fp32

    char* ws = (char*)d_ws;
    const size_t UBYTES = (size_t)NB * NR * NJO * 2;  // 188,743,680 (bf16 u_hat)
    uint32* u   = (uint32*)ws;
    float* s0   = (float*)(ws + UBYTES);
    float* s1   = s0 + NB * NJO;
    float* s2   = s1 + NB * NJO;
    float* vsum = s2 + NB * NJO;

    // zero s0,s1,s2,vsum (contiguous)
    hipMemsetAsync(s0, 0, (size_t)4 * NB * NJO * sizeof(float), stream);

    // u_hat
    uhat_kernel<<<NR, 320, 0, stream>>>(x, W, u);

    // iter 0: c uniform -> s0 -> v0 (vsum = v0)
    pass_kernel<true><<<dim3(NR / 384, NB), 384, 0, stream>>>(u, nullptr, s0);
    squash_kernel<false><<<(NB * NJO) / 256, 256, 0, stream>>>(s0, vsum);

    // iter 1: b1 = u.v0 -> c1 -> s1 -> v1 (vsum = v0+v1)
    pass_kernel<false><<<dim3(NR / 384, NB), 384, 0, stream>>>(u, vsum, s1);
    squash_kernel<false><<<(NB * NJO) / 256, 256, 0, stream>>>(s1, vsum);

    // iter 2: b2 = u.(v0+v1) -> c2 -> s2 -> v2 = output
    pass_kernel<false><<<dim3(NR / 384, NB), 384, 0, stream>>>(u, vsum, s2);
    squash_kernel<true><<<(NB * NJO) / 256, 256, 0, stream>>>(s2, out);
}

// Round 2
// 265.252 us; speedup vs baseline: 18.8630x; 18.8630x over previous
//
#include <hip/hip_runtime.h>
#include <hip/hip_bf16.h>
#include <cstdint>
#include <cstddef>

// Problem constants
#define NB 512
#define NR 1152
#define NC 8
#define NJ 10
#define NO 16
#define NJO 160   // NJ*NO

typedef unsigned int uint32;

// ---- bf16 helpers (RNE pack, bit-shift unpack) ----
__device__ __forceinline__ uint32 f2bf(float f) {
    uint32 x = __float_as_uint(f);
    return (x + 0x7fffu + ((x >> 16) & 1u)) >> 16;
}
__device__ __forceinline__ float bflo(uint32 w) { return __uint_as_float(w << 16); }
__device__ __forceinline__ float bfhi(uint32 w) { return __uint_as_float(w & 0xffff0000u); }

// k must be a compile-time-foldable expression (fully unrolled loops only)
#define UVAL(k) (((k) & 1) ? bfhi(u32[(k) >> 1]) : bflo(u32[(k) >> 1]))

// ============================================================================
// Kernel 1: u_hat[b,r,j,o] = sum_c W[r,j,o,c] * x[b,r,c], stored bf16.
// One block per r. W[r] (5KB) -> LDS transposed [c][jo]; x[:,r,:] (16KB) -> LDS.
// ============================================================================
__global__ __launch_bounds__(320) void uhat_kernel(const float* __restrict__ x,
                                                   const float* __restrict__ W,
                                                   uint32* __restrict__ u /* packed bf16 pairs */) {
    const int r = blockIdx.x;
    const int t = threadIdx.x;

    __shared__ float Ws[NC][NJO];   // 5 KB, transposed: [c][jo]
    __shared__ float xs[NB][NC];    // 16 KB

    for (int i = t; i < NJO * NC; i += 320) {
        Ws[i & 7][i >> 3] = W[(size_t)r * (NJO * NC) + i];
    }
    for (int i = t; i < NB * NC; i += 320) {
        int b = i >> 3, c = i & 7;
        xs[b][c] = x[(size_t)b * (NR * NC) + r * NC + c];
    }
    __syncthreads();

    const int jo2  = t % 80;   // pair index: handles jo = 2*jo2, 2*jo2+1
    const int half = t / 80;   // 0..3

    float w0[8], w1[8];
#pragma unroll
    for (int c = 0; c < 8; ++c) {
        w0[c] = Ws[c][2 * jo2];
        w1[c] = Ws[c][2 * jo2 + 1];
    }

    for (int b = half; b < NB; b += 4) {
        const float4* xp = (const float4*)xs[b];
        float4 xa = xp[0], xb = xp[1];
        float a0 = w0[0] * xa.x + w0[1] * xa.y + w0[2] * xa.z + w0[3] * xa.w
                 + w0[4] * xb.x + w0[5] * xb.y + w0[6] * xb.z + w0[7] * xb.w;
        float a1 = w1[0] * xa.x + w1[1] * xa.y + w1[2] * xa.z + w1[3] * xa.w
                 + w1[4] * xb.x + w1[5] * xb.y + w1[6] * xb.z + w1[7] * xb.w;
        uint32 p = f2bf(a0) | (f2bf(a1) << 16);
        u[(size_t)(b * NR + r) * 80 + jo2] = p;
    }
}

// ============================================================================
// Routing pass kernel. ONE WAVE per block; one thread per (b, r).
// Grid = (R/64, B), block = 64.
//   b_ij(r,j) = sum_o u[r,j,o] * vsum[b,j,o]; c = softmax_j (UNIFORM: 1/J)
//   s[b,j,o] += sum_r c(r,j) * u[r,j,o]
// The r-sum (over the 64 lanes) uses a butterfly REDUCE-SCATTER: 6 xor stages,
// exchanging the half of the live values the partner needs (96+48+24+12+6+3
// = 189 shuffles). Lane l ends owning the complete wave-sums for
// jo = 3*bitrev6(l) + {0,1,2}; one global atomicAdd each (18 blocks per b).
// ============================================================================
template <bool UNIFORM>
__global__ __launch_bounds__(64) void pass_kernel(const uint32* __restrict__ u,
                                                  const float* __restrict__ vsum,
                                                  float* __restrict__ s) {
    const int b    = blockIdx.y;
    const int lane = threadIdx.x;          // 0..63 (single wave)
    const int r    = blockIdx.x * 64 + lane;

    __shared__ float vs[NJO];
    if (!UNIFORM) {
        for (int i = lane; i < NJO; i += 64) vs[i] = vsum[b * NJO + i];
        __syncthreads();
    }

    // load this (b,r)'s 160 bf16 u values: 20 x dwordx4, fully coalesced
    uint32 u32[80];
    const uint4* up = (const uint4*)(u + (size_t)(b * NR + r) * 80);
#pragma unroll
    for (int i = 0; i < 20; ++i) {
        uint4 q = up[i];
        u32[4 * i + 0] = q.x;
        u32[4 * i + 1] = q.y;
        u32[4 * i + 2] = q.z;
        u32[4 * i + 3] = q.w;
    }

    float cj[NJ];
    if (UNIFORM) {
#pragma unroll
        for (int j = 0; j < NJ; ++j) cj[j] = 1.0f / NJ;
    } else {
        float bj[NJ];
        const float4* vp = (const float4*)vs;
#pragma unroll
        for (int j = 0; j < NJ; ++j) {
            float acc = 0.0f;
#pragma unroll
            for (int q = 0; q < 4; ++q) {
                float4 v4 = vp[j * 4 + q];
                acc += v4.x * UVAL(j * 16 + q * 4 + 0);
                acc += v4.y * UVAL(j * 16 + q * 4 + 1);
                acc += v4.z * UVAL(j * 16 + q * 4 + 2);
                acc += v4.w * UVAL(j * 16 + q * 4 + 3);
            }
            bj[j] = acc;
        }
        float m = bj[0];
#pragma unroll
        for (int j = 1; j < NJ; ++j) m = fmaxf(m, bj[j]);
        float sum = 0.0f;
#pragma unroll
        for (int j = 0; j < NJ; ++j) {
            float e = __expf(bj[j] - m);
            cj[j] = e;
            sum += e;
        }
        float inv = 1.0f / sum;
#pragma unroll
        for (int j = 0; j < NJ; ++j) cj[j] *= inv;
    }

    // contribution k (k in [0,192), padded past 160 with zeros)
    auto contrib = [&](int k) -> float {
        if (k >= NJO) return 0.0f;
        return cj[k >> 4] * UVAL(k);
    };

    // ---- reduce-scatter over the 64 lanes ----
    float a[96];
    {
        const int bit = lane & 1;
#pragma unroll
        for (int i = 0; i < 96; ++i) {
            float lo = contrib(i);
            float hi = contrib(i + 96);
            float send = bit ? lo : hi;
            float recv = __shfl_xor(send, 1);
            a[i] = (bit ? hi : lo) + recv;
        }
    }
#pragma unroll
    for (int st = 1; st < 6; ++st) {
        const int h = 96 >> st;              // 48,24,12,6,3
        const int bit = (lane >> st) & 1;
#pragma unroll
        for (int i = 0; i < 48; ++i) {
            if (i < h) {
                float send = bit ? a[i] : a[i + h];
                float recv = __shfl_xor(send, 1 << st);
                a[i] = (bit ? a[i + h] : a[i]) + recv;
            }
        }
    }

    // lane owns jo = 3*bitrev6(lane) + {0,1,2}
    const int base = 3 * (__brev((uint32)lane) >> 26);
#pragma unroll
    for (int i = 0; i < 3; ++i) {
        int jo = base + i;
        if (jo < NJO) atomicAdd(&s[b * NJO + jo], a[i]);
    }
}

// ============================================================================
// Squash: per (b,j): sq = sum_o s^2; v = (sq/(1+sq)) * s * rsqrt(sq + 1e-8).
// FINAL=false: vacc += v (running vsum). FINAL=true: write v to out.
// ============================================================================
template <bool FINAL>
__global__ __launch_bounds__(256) void squash_kernel(const float* __restrict__ s,
                                                     float* __restrict__ vacc) {
    const int idx = blockIdx.x * 256 + threadIdx.x;  // < 81920
    float val = s[idx];
    float sq = val * val;
#pragma unroll
    for (int off = 1; off < 16; off <<= 1) sq += __shfl_xor(sq, off, 16);
    float scale = (sq / (1.0f + sq)) * rsqrtf(sq + 1e-8f);
    float v = val * scale;
    if (FINAL) vacc[idx] = v;
    else       vacc[idx] += v;
}

// ============================================================================
extern "C" void kernel_launch(void* const* d_in, const int* in_sizes, int n_in,
                              void* d_out, int out_size, void* d_ws, size_t ws_size,
                              hipStream_t stream) {
    (void)in_sizes; (void)n_in; (void)out_size; (void)ws_size;

    const float* x = (const float*)d_in[0];  // [B,R,C]
    const float* W = (const float*)d_in[1];  // [R,J,O,C]
    float* out = (float*)d_out;              // [B,J,O,1] fp32

    char* ws = (char*)d_ws;
    const size_t UBYTES = (size_t)NB * NR * NJO * 2;  // 188,743,680 (bf16 u_hat)
    uint32* u   = (uint32*)ws;
    float* s0   = (float*)(ws + UBYTES);
    float* s1   = s0 + NB * NJO;
    float* s2   = s1 + NB * NJO;
    float* vsum = s2 + NB * NJO;

    // zero s0,s1,s2,vsum (contiguous)
    hipMemsetAsync(s0, 0, (size_t)4 * NB * NJO * sizeof(float), stream);

    // u_hat
    uhat_kernel<<<NR, 320, 0, stream>>>(x, W, u);

    // iter 0: c uniform -> s0 -> v0 (vsum = v0)
    pass_kernel<true><<<dim3(NR / 64, NB), 64, 0, stream>>>(u, nullptr, s0);
    squash_kernel<false><<<(NB * NJO) / 256, 256, 0, stream>>>(s0, vsum);

    // iter 1: b1 = u.v0 -> c1 -> s1 -> v1 (vsum = v0+v1)
    pass_kernel<false><<<dim3(NR / 64, NB), 64, 0, stream>>>(u, vsum, s1);
    squash_kernel<false><<<(NB * NJO) / 256, 256, 0, stream>>>(s1, vsum);

    // iter 2: b2 = u.(v0+v1) -> c2 -> s2 -> v2 = output
    pass_kernel<false><<<dim3(NR / 64, NB), 64, 0, stream>>>(u, vsum, s2);
    squash_kernel<true><<<(NB * NJO) / 256, 256, 0, stream>>>(s2, out);
}